// Round 10
// baseline (284.389 us; speedup 1.0000x reference)
//
#include <hip/hip_runtime.h>
#include <hip/hip_bf16.h>

// BatchedSemiAttention: B=2, N=50000, E=800000, INP=128, KEY=64, VAL=128
#define NB    2
#define NNODE 50000
#define NEDGE 800000
#define INPD  128
#define KEYD  64
#define VALD  128
#define MTOT  (NB * NNODE)   // 100000 flattened (b,n) rows
#define VBLK  3125           // NNODE/16 blocks for the values GEMM part
#define EPT   8              // edges per scatter thread
#define SBLK  ((NEDGE + 256 * EPT - 1) / (256 * EPT))   // 391 scatter blocks (run FIRST)
#define NSUB  8              // sub-buckets per receiver, keyed by blockIdx&7 (~XCD id):
                             // single-XCD writer per edge_s line -> coalesced writebacks
#define SUBCAP 16            // per-sub capacity; fill ~Poisson(2), P(any overflow) ~2e-4
#define ECAP  (NSUB * SUBCAP)   // 128 slots per receiver bucket

typedef __attribute__((ext_vector_type(8))) short bf16x8;
typedef __attribute__((ext_vector_type(4))) float f32x4;

__device__ __forceinline__ unsigned short f2bf(float f) {
    unsigned u = __float_as_uint(f);
    u += 0x7FFFu + ((u >> 16) & 1u);   // RNE
    return (unsigned short)(u >> 16);
}

// ---------------------------------------------------------------------------
// Prep: bf16 transposes of v_w / out_w into [n][k]; kwsum (col-sums of k_w,
// +kb sum at [128]); init the 8-way sub-cursors:
//   cursor[r*8+s] = r*ECAP + s*SUBCAP.
// ---------------------------------------------------------------------------
__global__ void prep_kernel(const float* __restrict__ kw, const float* __restrict__ kb,
                            const float* __restrict__ vw, const float* __restrict__ ow,
                            float* __restrict__ kwsum,
                            unsigned short* __restrict__ vwT, unsigned short* __restrict__ owT,
                            int* __restrict__ cursor) {
    int bid = blockIdx.x, tid = threadIdx.x;
    if (bid < 64) {
        int idx = bid * 256 + tid;            // [0,16384)
        int n = idx >> 7, k = idx & 127;
        vwT[idx] = f2bf(vw[k * VALD + n]);
    } else if (bid < 128) {
        int idx = (bid - 64) * 256 + tid;
        int n = idx >> 7, k = idx & 127;
        owT[idx] = f2bf(ow[k * VALD + n]);
    } else if (bid == 128) {
        if (tid < INPD) {
            float s = 0.f;
            for (int j = 0; j < KEYD; ++j) s += kw[tid * KEYD + j];
            kwsum[tid] = s;
        }
        if (tid == 0) {
            float s = 0.f;
            for (int j = 0; j < KEYD; ++j) s += kb[j];
            kwsum[INPD] = s;                  // kbsum
        }
    } else {
        int idx = (bid - 129) * 256 + tid;
        if (idx < NNODE * NSUB)
            cursor[idx] = (idx >> 3) * ECAP + (idx & (NSUB - 1)) * SUBCAP;
    }
}

// ---------------------------------------------------------------------------
// Values GEMM (both batches, 16 nodes/block, 256 threads) + ksum, with the
// EDGE SCATTER fused as the FIRST SBLK blocks (EPT=8 chains/thread).
// Sub-bucket key = blockIdx.x & 7 (~XCD under round-robin dispatch): every
// edge_s line is written by ONE XCD's L2 -> full-line coalesced writebacks
// instead of ~800K cross-XCD partial-line writebacks (the round-8 floor).
//   xs  [32][136] bf16  - x tile converted to bf16 at stage time (+8 pad)
//   pk  [16][264] u16   - packed output tile (+8 pad kills 8-way conflicts)
// values_pk layout per node (consumed by aggregate): 64 x uint2
// { b0 cols(2l,2l+1) bf16x2, b1 cols(2l,2l+1) bf16x2 }.
// ---------------------------------------------------------------------------
__global__ __launch_bounds__(256, 8)
void values_build_kernel(const float* __restrict__ x, const float* __restrict__ vb,
                         const float* __restrict__ kwsum,
                         const unsigned short* __restrict__ vwT,
                         const int* __restrict__ rows_e, const int* __restrict__ cols_e,
                         const float* __restrict__ conn,
                         uint2* __restrict__ values_pk, float* __restrict__ ksum,
                         int* __restrict__ cursor, uint2* __restrict__ edge_s) {
    __shared__ unsigned short xs[32 * 136];   // 8704 B, row stride 272 B
    __shared__ unsigned short pk[16 * 264];   // 8448 B, node stride 528 B
    int tid = threadIdx.x;
    if (blockIdx.x < SBLK) {
        int sub = blockIdx.x & (NSUB - 1);    // ~XCD id under round-robin dispatch
        int base = blockIdx.x * 256 + tid;
#pragma unroll
        for (int k = 0; k < EPT; ++k) {
            int e = base + k * (SBLK * 256);
            if (e < NEDGE) {
                int r = rows_e[e];
                int o = atomicAdd(&cursor[r * NSUB + sub], 1);
                if (o < r * ECAP + sub * SUBCAP + SUBCAP)   // overflow guard (~never)
                    edge_s[o] = make_uint2((unsigned)cols_e[e], __float_as_uint(conn[e]));
            }
        }
        return;
    }
    int node0 = (blockIdx.x - SBLK) * 16;

    // ---- stage: 8 fp32 per batch per thread -> bf16 LDS; fp32 ksum partials
    {
        int row = tid >> 4;            // node_local 0..15
        int cseg = tid & 15;           // 8-float column segment
        const float4* p0 = (const float4*)(x + (size_t)(node0 + row) * INPD) + cseg * 2;
        const float4* p1 = (const float4*)(x + (size_t)(NNODE + node0 + row) * INPD) + cseg * 2;
        float4 u0 = p0[0], u1 = p0[1];
        float4 w0 = p1[0], w1 = p1[1];
        const float4* kwp = (const float4*)kwsum + cseg * 2;
        float4 ka = kwp[0], kc = kwp[1];
        float kp0 = u0.x * ka.x + u0.y * ka.y + u0.z * ka.z + u0.w * ka.w
                  + u1.x * kc.x + u1.y * kc.y + u1.z * kc.z + u1.w * kc.w;
        float kp1 = w0.x * ka.x + w0.y * ka.y + w0.z * ka.z + w0.w * ka.w
                  + w1.x * kc.x + w1.y * kc.y + w1.z * kc.z + w1.w * kc.w;
#pragma unroll
        for (int o = 1; o < 16; o <<= 1) {
            kp0 += __shfl_xor(kp0, o);
            kp1 += __shfl_xor(kp1, o);
        }
        if (cseg == 0) {
            float kb = kwsum[INPD];
            ksum[node0 + row] = kp0 + kb;
            ksum[NNODE + node0 + row] = kp1 + kb;
        }
        union { unsigned short h[8]; uint4 q; } a, b;
        a.h[0] = f2bf(u0.x); a.h[1] = f2bf(u0.y); a.h[2] = f2bf(u0.z); a.h[3] = f2bf(u0.w);
        a.h[4] = f2bf(u1.x); a.h[5] = f2bf(u1.y); a.h[6] = f2bf(u1.z); a.h[7] = f2bf(u1.w);
        b.h[0] = f2bf(w0.x); b.h[1] = f2bf(w0.y); b.h[2] = f2bf(w0.z); b.h[3] = f2bf(w0.w);
        b.h[4] = f2bf(w1.x); b.h[5] = f2bf(w1.y); b.h[6] = f2bf(w1.z); b.h[7] = f2bf(w1.w);
        *(uint4*)(xs + row * 136 + cseg * 8) = a.q;
        *(uint4*)(xs + (16 + row) * 136 + cseg * 8) = b.q;
    }
    __syncthreads();

    int wave = tid >> 6, lane = tid & 63;
    int m = lane & 15, quad = lane >> 4;
    int n0 = wave * 32;                       // this wave's 32-col slice
    f32x4 acc00 = {0.f, 0.f, 0.f, 0.f};      // batch0, cols n0+m
    f32x4 acc01 = {0.f, 0.f, 0.f, 0.f};      // batch0, cols n0+16+m
    f32x4 acc10 = {0.f, 0.f, 0.f, 0.f};      // batch1, cols n0+m
    f32x4 acc11 = {0.f, 0.f, 0.f, 0.f};      // batch1, cols n0+16+m
    const unsigned short* r0 = xs + m * 136;
    const unsigned short* r1 = xs + (16 + m) * 136;
    const unsigned short* bw0 = vwT + (size_t)(n0 + m) * INPD;
    const unsigned short* bw1 = vwT + (size_t)(n0 + 16 + m) * INPD;
#pragma unroll
    for (int kk = 0; kk < 4; ++kk) {
        int k0 = kk * 32 + quad * 8;
        bf16x8 A0 = *(const bf16x8*)(r0 + k0);
        bf16x8 A1 = *(const bf16x8*)(r1 + k0);
        bf16x8 B0 = *(const bf16x8*)(bw0 + k0);
        bf16x8 B1 = *(const bf16x8*)(bw1 + k0);
        acc00 = __builtin_amdgcn_mfma_f32_16x16x32_bf16(A0, B0, acc00, 0, 0, 0);
        acc01 = __builtin_amdgcn_mfma_f32_16x16x32_bf16(A0, B1, acc01, 0, 0, 0);
        acc10 = __builtin_amdgcn_mfma_f32_16x16x32_bf16(A1, B0, acc10, 0, 0, 0);
        acc11 = __builtin_amdgcn_mfma_f32_16x16x32_bf16(A1, B1, acc11, 0, 0, 0);
    }
    int c0 = n0 + m, c1 = n0 + 16 + m;
    float vb0 = vb[c0], vb1 = vb[c1];
    int p0 = (c0 >> 1) * 4 + (c0 & 1);        // ushort index within node's 256
    int p1 = (c1 >> 1) * 4 + (c1 & 1);
#pragma unroll
    for (int r = 0; r < 4; ++r) {
        int nl = quad * 4 + r;                // node_local
        pk[nl * 264 + p0]     = f2bf(acc00[r] + vb0);   // batch 0
        pk[nl * 264 + p0 + 2] = f2bf(acc10[r] + vb0);   // batch 1
        pk[nl * 264 + p1]     = f2bf(acc01[r] + vb1);
        pk[nl * 264 + p1 + 2] = f2bf(acc11[r] + vb1);
    }
    __syncthreads();
    // Coalesced flush skipping the pads: 2 x uint4 per thread = 8 KB.
    {
        int node = tid >> 4, chunk = tid & 15;
        uint4 q0 = *(const uint4*)(pk + node * 264 + chunk * 8);
        uint4 q1 = *(const uint4*)(pk + node * 264 + (chunk + 16) * 8);
        uint4* dst = (uint4*)((char*)values_pk + (size_t)node0 * 512) + node * 32;
        dst[chunk] = q0;
        dst[chunk + 16] = q1;
    }
}

// ---------------------------------------------------------------------------
// Per-receiver softmax + weighted aggregation. 2 rows per wave; verified
// round-4/8 shfl-softmax + x4 gather body. Edge sourcing: read the 8 sub-
// cursors (2x int4), prefix the 8 sub-lengths, lane->(sub,idx) remap —
// extension of the round-9 correctness-verified 4-way remap. len <= ~45
// always (Poisson(16)); clamp guards the impossible overflow case.
// ---------------------------------------------------------------------------
__global__ __launch_bounds__(256)
void aggregate_kernel(const int* __restrict__ cursor,
                      const uint2* __restrict__ edge_s,
                      const float* __restrict__ ksum,
                      const uint2* __restrict__ values_pk,
                      unsigned short* __restrict__ agg_bf) {
    int wave = threadIdx.x >> 6, lane = threadIdx.x & 63;
    int wid = blockIdx.x * 4 + wave;
    for (int rr = 0; rr < 2; ++rr) {
        int i = wid * 2 + rr;
        if (i >= NNODE) break;
        int base0 = i * ECAP;
        int4 ca = *(const int4*)(cursor + i * NSUB);
        int4 cb = *(const int4*)(cursor + i * NSUB + 4);
        int l0 = min(ca.x - base0,                 SUBCAP);
        int l1 = min(ca.y - (base0 + 1 * SUBCAP),  SUBCAP);
        int l2 = min(ca.z - (base0 + 2 * SUBCAP),  SUBCAP);
        int l3 = min(ca.w - (base0 + 3 * SUBCAP),  SUBCAP);
        int l4 = min(cb.x - (base0 + 4 * SUBCAP),  SUBCAP);
        int l5 = min(cb.y - (base0 + 5 * SUBCAP),  SUBCAP);
        int l6 = min(cb.z - (base0 + 6 * SUBCAP),  SUBCAP);
        int l7 = min(cb.w - (base0 + 7 * SUBCAP),  SUBCAP);
        int t1 = l0, t2 = t1 + l1, t3 = t2 + l2, t4 = t3 + l3;
        int t5 = t4 + l4, t6 = t5 + l5, t7 = t6 + l6;
        int len = t7 + l7;
        if (len > 64) len = 64;               // statistically impossible; safety
        float acc00 = 0.f, acc01 = 0.f, acc10 = 0.f, acc11 = 0.f;
        if (len > 0) {
            float ex0 = 0.f, ex1 = 0.f; int colv = 0;
            if (lane < len) {
                int s, idx;
                if (lane < t1)      { s = 0; idx = lane; }
                else if (lane < t2) { s = 1; idx = lane - t1; }
                else if (lane < t3) { s = 2; idx = lane - t2; }
                else if (lane < t4) { s = 3; idx = lane - t3; }
                else if (lane < t5) { s = 4; idx = lane - t4; }
                else if (lane < t6) { s = 5; idx = lane - t5; }
                else if (lane < t7) { s = 6; idx = lane - t6; }
                else                { s = 7; idx = lane - t7; }
                uint2 e = edge_s[base0 + s * SUBCAP + idx];
                colv = (int)e.x;
                float cv = __uint_as_float(e.y);
                ex0 = __expf(cv * ksum[colv]);
                ex1 = __expf(cv * ksum[NNODE + colv]);
            }
            float s0 = ex0, s1 = ex1;
#pragma unroll
            for (int o = 1; o < 64; o <<= 1) { s0 += __shfl_xor(s0, o); s1 += __shfl_xor(s1, o); }
            float inv0 = 1.0f / s0, inv1 = 1.0f / s1;
            int p = 0;
            for (; p + 3 < len; p += 4) {
                int c0 = __shfl(colv, p),     c1 = __shfl(colv, p + 1);
                int c2 = __shfl(colv, p + 2), c3 = __shfl(colv, p + 3);
                float wa0 = __shfl(ex0, p) * inv0,     wb0 = __shfl(ex1, p) * inv1;
                float wa1 = __shfl(ex0, p + 1) * inv0, wb1 = __shfl(ex1, p + 1) * inv1;
                float wa2 = __shfl(ex0, p + 2) * inv0, wb2 = __shfl(ex1, p + 2) * inv1;
                float wa3 = __shfl(ex0, p + 3) * inv0, wb3 = __shfl(ex1, p + 3) * inv1;
                uint2 v0 = values_pk[(size_t)c0 * 64 + lane];
                uint2 v1 = values_pk[(size_t)c1 * 64 + lane];
                uint2 v2 = values_pk[(size_t)c2 * 64 + lane];
                uint2 v3 = values_pk[(size_t)c3 * 64 + lane];
                acc00 += wa0 * __uint_as_float(v0.x << 16) + wa1 * __uint_as_float(v1.x << 16)
                       + wa2 * __uint_as_float(v2.x << 16) + wa3 * __uint_as_float(v3.x << 16);
                acc01 += wa0 * __uint_as_float(v0.x & 0xFFFF0000u) + wa1 * __uint_as_float(v1.x & 0xFFFF0000u)
                       + wa2 * __uint_as_float(v2.x & 0xFFFF0000u) + wa3 * __uint_as_float(v3.x & 0xFFFF0000u);
                acc10 += wb0 * __uint_as_float(v0.y << 16) + wb1 * __uint_as_float(v1.y << 16)
                       + wb2 * __uint_as_float(v2.y << 16) + wb3 * __uint_as_float(v3.y << 16);
                acc11 += wb0 * __uint_as_float(v0.y & 0xFFFF0000u) + wb1 * __uint_as_float(v1.y & 0xFFFF0000u)
                       + wb2 * __uint_as_float(v2.y & 0xFFFF0000u) + wb3 * __uint_as_float(v3.y & 0xFFFF0000u);
            }
            for (; p < len; ++p) {
                int c = __shfl(colv, p);
                float w0 = __shfl(ex0, p) * inv0;
                float w1 = __shfl(ex1, p) * inv1;
                uint2 v = values_pk[(size_t)c * 64 + lane];
                acc00 += w0 * __uint_as_float(v.x << 16);
                acc01 += w0 * __uint_as_float(v.x & 0xFFFF0000u);
                acc10 += w1 * __uint_as_float(v.y << 16);
                acc11 += w1 * __uint_as_float(v.y & 0xFFFF0000u);
            }
        }
        unsigned o0 = ((unsigned)f2bf(acc01) << 16) | (unsigned)f2bf(acc00);
        unsigned o1 = ((unsigned)f2bf(acc11) << 16) | (unsigned)f2bf(acc10);
        ((unsigned*)(agg_bf + (size_t)i * VALD))[lane] = o0;
        ((unsigned*)(agg_bf + (size_t)(NNODE + i) * VALD))[lane] = o1;
    }
}

// ---------------------------------------------------------------------------
// out = LN(silu(agg @ out_w + out_b)) * g + b. 16 rows x 128 cols per block.
// ---------------------------------------------------------------------------
__global__ __launch_bounds__(256)
void out_kernel(const unsigned short* __restrict__ agg_bf,
                const unsigned short* __restrict__ owT,
                const float* __restrict__ ob,
                const float* __restrict__ lng, const float* __restrict__ lnb,
                float* __restrict__ out) {
    __shared__ float hs[16][VALD + 2];
    __shared__ float ps[16][16];
    __shared__ float psq[16][16];
    __shared__ float mu_s[16], rs_s[16];
    int m0 = blockIdx.x * 16;
    int tid = threadIdx.x;
    int wave = tid >> 6, lane = tid & 63;
    int m = lane & 15, quad = lane >> 4;
    int n0 = wave * 32;
    f32x4 a0 = {0.f, 0.f, 0.f, 0.f}, a1 = {0.f, 0.f, 0.f, 0.f};
    const unsigned short* arow = agg_bf + (size_t)(m0 + m) * VALD;
#pragma unroll
    for (int kk = 0; kk < 4; ++kk) {
        int k0 = kk * 32 + quad * 8;
        bf16x8 af = *(const bf16x8*)(arow + k0);
        bf16x8 b0 = *(const bf16x8*)(owT + (size_t)(n0 + m) * VALD + k0);
        bf16x8 b1 = *(const bf16x8*)(owT + (size_t)(n0 + 16 + m) * VALD + k0);
        a0 = __builtin_amdgcn_mfma_f32_16x16x32_bf16(af, b0, a0, 0, 0, 0);
        a1 = __builtin_amdgcn_mfma_f32_16x16x32_bf16(af, b1, a1, 0, 0, 0);
    }
#pragma unroll
    for (int r = 0; r < 4; ++r) {
        int row = quad * 4 + r;
        {
            int col = n0 + m;
            float h = a0[r] + ob[col];
            hs[row][col] = h / (1.f + __expf(-h));
        }
        {
            int col = n0 + 16 + m;
            float h = a1[r] + ob[col];
            hs[row][col] = h / (1.f + __expf(-h));
        }
    }
    __syncthreads();
    {
        int row = tid >> 4, seg = tid & 15;
        float s = 0.f, q = 0.f;
#pragma unroll
        for (int j = 0; j < 8; ++j) {
            float v = hs[row][seg * 8 + j];
            s += v; q += v * v;
        }
        ps[row][seg] = s; psq[row][seg] = q;
    }
    __syncthreads();
    if (tid < 16) {
        float s = 0.f, q = 0.f;
#pragma unroll
        for (int j = 0; j < 16; ++j) { s += ps[tid][j]; q += psq[tid][j]; }
        float mu = s * (1.f / 128.f);
        float var = q * (1.f / 128.f) - mu * mu;
        mu_s[tid] = mu;
        rs_s[tid] = rsqrtf(var + 1e-5f);
    }
    __syncthreads();
#pragma unroll
    for (int j = 0; j < 8; ++j) {
        int e = tid + 256 * j;
        int row = e >> 7, col = e & 127;
        out[(size_t)(m0 + row) * VALD + col] =
            (hs[row][col] - mu_s[row]) * rs_s[row] * lng[col] + lnb[col];
    }
}

// ---------------------------------------------------------------------------
extern "C" void kernel_launch(void* const* d_in, const int* in_sizes, int n_in,
                              void* d_out, int out_size, void* d_ws, size_t ws_size,
                              hipStream_t stream) {
    (void)in_sizes; (void)n_in; (void)out_size; (void)ws_size;
    const float* x    = (const float*)d_in[0];
    const float* conn = (const float*)d_in[1];
    const float* kw   = (const float*)d_in[2];
    const float* kb   = (const float*)d_in[3];
    const float* vw   = (const float*)d_in[4];
    const float* vb   = (const float*)d_in[5];
    const float* ow   = (const float*)d_in[6];
    const float* ob   = (const float*)d_in[7];
    const float* lng  = (const float*)d_in[8];
    const float* lnb  = (const float*)d_in[9];
    const int* rows   = (const int*)d_in[10];
    const int* cols   = (const int*)d_in[11];
    float* out        = (float*)d_out;

    char* w = (char*)d_ws;
    auto alloc = [&](size_t bytes) {
        char* p = w;
        w += (bytes + 255) & ~(size_t)255;
        return p;
    };
    uint2* values_pk       = (uint2*)alloc((size_t)NNODE * 512);              // 25.6 MB
    unsigned short* agg_bf = (unsigned short*)alloc((size_t)MTOT * VALD * 2); // 25.6 MB
    float* ksum   = (float*)alloc((size_t)MTOT * 4);
    float* kwsum  = (float*)alloc(256 * 4);
    int*   cursor = (int*)alloc((size_t)NNODE * NSUB * 4);                    // 1.6 MB
    uint2* edge_s = (uint2*)alloc((size_t)NNODE * ECAP * 8);                  // 51.2 MB
    unsigned short* vwT = (unsigned short*)alloc((size_t)INPD * VALD * 2);
    unsigned short* owT = (unsigned short*)alloc((size_t)VALD * VALD * 2);

    prep_kernel<<<129 + 1563, 256, 0, stream>>>(kw, kb, vw, ow, kwsum, vwT, owT, cursor);
    values_build_kernel<<<SBLK + VBLK, 256, 0, stream>>>(
        x, vb, kwsum, vwT, rows, cols, conn, values_pk, ksum, cursor, edge_s);
    aggregate_kernel<<<(NNODE + 7) / 8, 256, 0, stream>>>(
        cursor, edge_s, ksum, values_pk, agg_bf);
    out_kernel<<<MTOT / 16, 256, 0, stream>>>(agg_bf, owT, ob, lng, lnb, out);
}

// Round 11
// 264.232 us; speedup vs baseline: 1.0763x; 1.0763x over previous
//
#include <hip/hip_runtime.h>
#include <hip/hip_bf16.h>

// BatchedSemiAttention: B=2, N=50000, E=800000, INP=128, KEY=64, VAL=128
#define NB    2
#define NNODE 50000
#define NEDGE 800000
#define INPD  128
#define KEYD  64
#define VALD  128
#define MTOT  (NB * NNODE)   // 100000 flattened (b,n) rows
#define VBLK  3125           // NNODE/16 blocks for the values GEMM part
#define EPT   16             // edges per scatter thread (16 independent chains)
#define SBLK  ((NEDGE + 256 * EPT - 1) / (256 * EPT))   // 196 scatter blocks (run FIRST)
#define ECAP  80             // bucket capacity per receiver; E/N=16 Poisson, max~40

typedef __attribute__((ext_vector_type(8))) short bf16x8;
typedef __attribute__((ext_vector_type(4))) float f32x4;

__device__ __forceinline__ unsigned short f2bf(float f) {
    unsigned u = __float_as_uint(f);
    u += 0x7FFFu + ((u >> 16) & 1u);   // RNE
    return (unsigned short)(u >> 16);
}

// ---------------------------------------------------------------------------
// Prep: bf16 transposes of v_w / out_w into [n][k]; kwsum (col-sums of k_w,
// +kb sum at [128]); init the fixed-base edge cursors (cursor[i] = i*ECAP).
// ---------------------------------------------------------------------------
__global__ void prep_kernel(const float* __restrict__ kw, const float* __restrict__ kb,
                            const float* __restrict__ vw, const float* __restrict__ ow,
                            float* __restrict__ kwsum,
                            unsigned short* __restrict__ vwT, unsigned short* __restrict__ owT,
                            int* __restrict__ cursor) {
    int bid = blockIdx.x, tid = threadIdx.x;
    if (bid < 64) {
        int idx = bid * 256 + tid;            // [0,16384)
        int n = idx >> 7, k = idx & 127;
        vwT[idx] = f2bf(vw[k * VALD + n]);
    } else if (bid < 128) {
        int idx = (bid - 64) * 256 + tid;
        int n = idx >> 7, k = idx & 127;
        owT[idx] = f2bf(ow[k * VALD + n]);
    } else if (bid == 128) {
        if (tid < INPD) {
            float s = 0.f;
            for (int j = 0; j < KEYD; ++j) s += kw[tid * KEYD + j];
            kwsum[tid] = s;
        }
        if (tid == 0) {
            float s = 0.f;
            for (int j = 0; j < KEYD; ++j) s += kb[j];
            kwsum[INPD] = s;                  // kbsum
        }
    } else {
        int idx = (bid - 129) * 256 + tid;
        if (idx < NNODE) cursor[idx] = idx * ECAP;
    }
}

// ---------------------------------------------------------------------------
// Values GEMM (both batches, 16 nodes/block, 256 threads) + ksum, with the
// EDGE SCATTER fused as the FIRST SBLK blocks (EPT=16 chains/thread).
// edge_s writes are NONTEMPORAL: each 8-B write hits a random 64-B line that
// is never re-read before the next kernel -- nt skips write-allocate/RFO on
// the per-line random-scatter cost identified as the r8-r10 floor.
// Fixed-capacity buckets: slot = atomicAdd(cursor[r]), cursor pre-based r*ECAP.
//   xs  [32][136] bf16  - x tile converted to bf16 at stage time (+8 pad)
//   pk  [16][264] u16   - packed output tile (+8 pad kills 8-way conflicts)
// values_pk layout per node (consumed by aggregate): 64 x uint2
// { b0 cols(2l,2l+1) bf16x2, b1 cols(2l,2l+1) bf16x2 }.
// ---------------------------------------------------------------------------
__global__ __launch_bounds__(256, 8)
void values_build_kernel(const float* __restrict__ x, const float* __restrict__ vb,
                         const float* __restrict__ kwsum,
                         const unsigned short* __restrict__ vwT,
                         const int* __restrict__ rows_e, const int* __restrict__ cols_e,
                         const float* __restrict__ conn,
                         uint2* __restrict__ values_pk, float* __restrict__ ksum,
                         int* __restrict__ cursor, uint2* __restrict__ edge_s) {
    __shared__ unsigned short xs[32 * 136];   // 8704 B, row stride 272 B
    __shared__ unsigned short pk[16 * 264];   // 8448 B, node stride 528 B
    int tid = threadIdx.x;
    if (blockIdx.x < SBLK) {
        int base = blockIdx.x * 256 + tid;
#pragma unroll
        for (int k = 0; k < EPT; ++k) {
            int e = base + k * (SBLK * 256);
            if (e < NEDGE) {
                int r = rows_e[e];
                int o = atomicAdd(&cursor[r], 1);
                if (o < r * ECAP + ECAP) {    // never false for real data
                    unsigned long long pkd =
                        (unsigned long long)(unsigned)cols_e[e]
                        | ((unsigned long long)__float_as_uint(conn[e]) << 32);
                    __builtin_nontemporal_store(
                        pkd, (unsigned long long*)&edge_s[o]);
                }
            }
        }
        return;
    }
    int node0 = (blockIdx.x - SBLK) * 16;

    // ---- stage: 8 fp32 per batch per thread -> bf16 LDS; fp32 ksum partials
    {
        int row = tid >> 4;            // node_local 0..15
        int cseg = tid & 15;           // 8-float column segment
        const float4* p0 = (const float4*)(x + (size_t)(node0 + row) * INPD) + cseg * 2;
        const float4* p1 = (const float4*)(x + (size_t)(NNODE + node0 + row) * INPD) + cseg * 2;
        float4 u0 = p0[0], u1 = p0[1];
        float4 w0 = p1[0], w1 = p1[1];
        const float4* kwp = (const float4*)kwsum + cseg * 2;
        float4 ka = kwp[0], kc = kwp[1];
        float kp0 = u0.x * ka.x + u0.y * ka.y + u0.z * ka.z + u0.w * ka.w
                  + u1.x * kc.x + u1.y * kc.y + u1.z * kc.z + u1.w * kc.w;
        float kp1 = w0.x * ka.x + w0.y * ka.y + w0.z * ka.z + w0.w * ka.w
                  + w1.x * kc.x + w1.y * kc.y + w1.z * kc.z + w1.w * kc.w;
#pragma unroll
        for (int o = 1; o < 16; o <<= 1) {
            kp0 += __shfl_xor(kp0, o);
            kp1 += __shfl_xor(kp1, o);
        }
        if (cseg == 0) {
            float kb = kwsum[INPD];
            ksum[node0 + row] = kp0 + kb;
            ksum[NNODE + node0 + row] = kp1 + kb;
        }
        union { unsigned short h[8]; uint4 q; } a, b;
        a.h[0] = f2bf(u0.x); a.h[1] = f2bf(u0.y); a.h[2] = f2bf(u0.z); a.h[3] = f2bf(u0.w);
        a.h[4] = f2bf(u1.x); a.h[5] = f2bf(u1.y); a.h[6] = f2bf(u1.z); a.h[7] = f2bf(u1.w);
        b.h[0] = f2bf(w0.x); b.h[1] = f2bf(w0.y); b.h[2] = f2bf(w0.z); b.h[3] = f2bf(w0.w);
        b.h[4] = f2bf(w1.x); b.h[5] = f2bf(w1.y); b.h[6] = f2bf(w1.z); b.h[7] = f2bf(w1.w);
        *(uint4*)(xs + row * 136 + cseg * 8) = a.q;
        *(uint4*)(xs + (16 + row) * 136 + cseg * 8) = b.q;
    }
    __syncthreads();

    int wave = tid >> 6, lane = tid & 63;
    int m = lane & 15, quad = lane >> 4;
    int n0 = wave * 32;                       // this wave's 32-col slice
    f32x4 acc00 = {0.f, 0.f, 0.f, 0.f};      // batch0, cols n0+m
    f32x4 acc01 = {0.f, 0.f, 0.f, 0.f};      // batch0, cols n0+16+m
    f32x4 acc10 = {0.f, 0.f, 0.f, 0.f};      // batch1, cols n0+m
    f32x4 acc11 = {0.f, 0.f, 0.f, 0.f};      // batch1, cols n0+16+m
    const unsigned short* r0 = xs + m * 136;
    const unsigned short* r1 = xs + (16 + m) * 136;
    const unsigned short* bw0 = vwT + (size_t)(n0 + m) * INPD;
    const unsigned short* bw1 = vwT + (size_t)(n0 + 16 + m) * INPD;
#pragma unroll
    for (int kk = 0; kk < 4; ++kk) {
        int k0 = kk * 32 + quad * 8;
        bf16x8 A0 = *(const bf16x8*)(r0 + k0);
        bf16x8 A1 = *(const bf16x8*)(r1 + k0);
        bf16x8 B0 = *(const bf16x8*)(bw0 + k0);
        bf16x8 B1 = *(const bf16x8*)(bw1 + k0);
        acc00 = __builtin_amdgcn_mfma_f32_16x16x32_bf16(A0, B0, acc00, 0, 0, 0);
        acc01 = __builtin_amdgcn_mfma_f32_16x16x32_bf16(A0, B1, acc01, 0, 0, 0);
        acc10 = __builtin_amdgcn_mfma_f32_16x16x32_bf16(A1, B0, acc10, 0, 0, 0);
        acc11 = __builtin_amdgcn_mfma_f32_16x16x32_bf16(A1, B1, acc11, 0, 0, 0);
    }
    int c0 = n0 + m, c1 = n0 + 16 + m;
    float vb0 = vb[c0], vb1 = vb[c1];
    int p0 = (c0 >> 1) * 4 + (c0 & 1);        // ushort index within node's 256
    int p1 = (c1 >> 1) * 4 + (c1 & 1);
#pragma unroll
    for (int r = 0; r < 4; ++r) {
        int nl = quad * 4 + r;                // node_local
        pk[nl * 264 + p0]     = f2bf(acc00[r] + vb0);   // batch 0
        pk[nl * 264 + p0 + 2] = f2bf(acc10[r] + vb0);   // batch 1
        pk[nl * 264 + p1]     = f2bf(acc01[r] + vb1);
        pk[nl * 264 + p1 + 2] = f2bf(acc11[r] + vb1);
    }
    __syncthreads();
    // Coalesced flush skipping the pads: 2 x uint4 per thread = 8 KB.
    {
        int node = tid >> 4, chunk = tid & 15;
        uint4 q0 = *(const uint4*)(pk + node * 264 + chunk * 8);
        uint4 q1 = *(const uint4*)(pk + node * 264 + (chunk + 16) * 8);
        uint4* dst = (uint4*)((char*)values_pk + (size_t)node0 * 512) + node * 32;
        dst[chunk] = q0;
        dst[chunk + 16] = q1;
    }
}

// ---------------------------------------------------------------------------
// Per-receiver softmax + weighted aggregation. 2 rows per wave, p-loop
// unrolled x4 for memory-level parallelism; one dwordx2 gather per edge
// covers both batches. No max-subtraction (|score| <= ~40, fp32-safe).
// (Round-4/8 verified body; start/len come from the fixed buckets.)
// ---------------------------------------------------------------------------
__global__ __launch_bounds__(256)
void aggregate_kernel(const int* __restrict__ cursor,
                      const uint2* __restrict__ edge_s,
                      const float* __restrict__ ksum,
                      const uint2* __restrict__ values_pk,
                      unsigned short* __restrict__ agg_bf) {
    int wave = threadIdx.x >> 6, lane = threadIdx.x & 63;
    int wid = blockIdx.x * 4 + wave;
    for (int rr = 0; rr < 2; ++rr) {
        int i = wid * 2 + rr;
        if (i >= NNODE) break;
        int start = i * ECAP;
        int len = min(cursor[i] - start, ECAP);
        float acc00 = 0.f, acc01 = 0.f, acc10 = 0.f, acc11 = 0.f;
        if (len > 0) {
            if (len <= 64) {
                float ex0 = 0.f, ex1 = 0.f; int colv = 0;
                if (lane < len) {
                    uint2 e = edge_s[start + lane];
                    colv = (int)e.x;
                    float cv = __uint_as_float(e.y);
                    ex0 = __expf(cv * ksum[colv]);
                    ex1 = __expf(cv * ksum[NNODE + colv]);
                }
                float s0 = ex0, s1 = ex1;
#pragma unroll
                for (int o = 1; o < 64; o <<= 1) { s0 += __shfl_xor(s0, o); s1 += __shfl_xor(s1, o); }
                float inv0 = 1.0f / s0, inv1 = 1.0f / s1;
                int p = 0;
                for (; p + 3 < len; p += 4) {
                    int c0 = __shfl(colv, p),     c1 = __shfl(colv, p + 1);
                    int c2 = __shfl(colv, p + 2), c3 = __shfl(colv, p + 3);
                    float wa0 = __shfl(ex0, p) * inv0,     wb0 = __shfl(ex1, p) * inv1;
                    float wa1 = __shfl(ex0, p + 1) * inv0, wb1 = __shfl(ex1, p + 1) * inv1;
                    float wa2 = __shfl(ex0, p + 2) * inv0, wb2 = __shfl(ex1, p + 2) * inv1;
                    float wa3 = __shfl(ex0, p + 3) * inv0, wb3 = __shfl(ex1, p + 3) * inv1;
                    uint2 v0 = values_pk[(size_t)c0 * 64 + lane];
                    uint2 v1 = values_pk[(size_t)c1 * 64 + lane];
                    uint2 v2 = values_pk[(size_t)c2 * 64 + lane];
                    uint2 v3 = values_pk[(size_t)c3 * 64 + lane];
                    acc00 += wa0 * __uint_as_float(v0.x << 16) + wa1 * __uint_as_float(v1.x << 16)
                           + wa2 * __uint_as_float(v2.x << 16) + wa3 * __uint_as_float(v3.x << 16);
                    acc01 += wa0 * __uint_as_float(v0.x & 0xFFFF0000u) + wa1 * __uint_as_float(v1.x & 0xFFFF0000u)
                           + wa2 * __uint_as_float(v2.x & 0xFFFF0000u) + wa3 * __uint_as_float(v3.x & 0xFFFF0000u);
                    acc10 += wb0 * __uint_as_float(v0.y << 16) + wb1 * __uint_as_float(v1.y << 16)
                           + wb2 * __uint_as_float(v2.y << 16) + wb3 * __uint_as_float(v3.y << 16);
                    acc11 += wb0 * __uint_as_float(v0.y & 0xFFFF0000u) + wb1 * __uint_as_float(v1.y & 0xFFFF0000u)
                           + wb2 * __uint_as_float(v2.y & 0xFFFF0000u) + wb3 * __uint_as_float(v3.y & 0xFFFF0000u);
                }
                for (; p < len; ++p) {
                    int c = __shfl(colv, p);
                    float w0 = __shfl(ex0, p) * inv0;
                    float w1 = __shfl(ex1, p) * inv1;
                    uint2 v = values_pk[(size_t)c * 64 + lane];
                    acc00 += w0 * __uint_as_float(v.x << 16);
                    acc01 += w0 * __uint_as_float(v.x & 0xFFFF0000u);
                    acc10 += w1 * __uint_as_float(v.y << 16);
                    acc11 += w1 * __uint_as_float(v.y & 0xFFFF0000u);
                }
            } else {
                float s0 = 0.f, s1 = 0.f;
                for (int basep = 0; basep < len; basep += 64) {
                    int q = basep + lane;
                    if (q < len) {
                        uint2 e = edge_s[start + q];
                        int c = (int)e.x;
                        float cv = __uint_as_float(e.y);
                        s0 += __expf(cv * ksum[c]);
                        s1 += __expf(cv * ksum[NNODE + c]);
                    }
                }
#pragma unroll
                for (int o = 1; o < 64; o <<= 1) { s0 += __shfl_xor(s0, o); s1 += __shfl_xor(s1, o); }
                float inv0 = 1.0f / s0, inv1 = 1.0f / s1;
                for (int p = 0; p < len; ++p) {
                    uint2 e = edge_s[start + p];
                    int c = (int)e.x;
                    float cv = __uint_as_float(e.y);
                    float w0 = __expf(cv * ksum[c]) * inv0;
                    float w1 = __expf(cv * ksum[NNODE + c]) * inv1;
                    uint2 v = values_pk[(size_t)c * 64 + lane];
                    acc00 += w0 * __uint_as_float(v.x << 16);
                    acc01 += w0 * __uint_as_float(v.x & 0xFFFF0000u);
                    acc10 += w1 * __uint_as_float(v.y << 16);
                    acc11 += w1 * __uint_as_float(v.y & 0xFFFF0000u);
                }
            }
        }
        unsigned o0 = ((unsigned)f2bf(acc01) << 16) | (unsigned)f2bf(acc00);
        unsigned o1 = ((unsigned)f2bf(acc11) << 16) | (unsigned)f2bf(acc10);
        ((unsigned*)(agg_bf + (size_t)i * VALD))[lane] = o0;
        ((unsigned*)(agg_bf + (size_t)(NNODE + i) * VALD))[lane] = o1;
    }
}

// ---------------------------------------------------------------------------
// out = LN(silu(agg @ out_w + out_b)) * g + b. 16 rows x 128 cols per block.
// ---------------------------------------------------------------------------
__global__ __launch_bounds__(256)
void out_kernel(const unsigned short* __restrict__ agg_bf,
                const unsigned short* __restrict__ owT,
                const float* __restrict__ ob,
                const float* __restrict__ lng, const float* __restrict__ lnb,
                float* __restrict__ out) {
    __shared__ float hs[16][VALD + 2];
    __shared__ float ps[16][16];
    __shared__ float psq[16][16];
    __shared__ float mu_s[16], rs_s[16];
    int m0 = blockIdx.x * 16;
    int tid = threadIdx.x;
    int wave = tid >> 6, lane = tid & 63;
    int m = lane & 15, quad = lane >> 4;
    int n0 = wave * 32;
    f32x4 a0 = {0.f, 0.f, 0.f, 0.f}, a1 = {0.f, 0.f, 0.f, 0.f};
    const unsigned short* arow = agg_bf + (size_t)(m0 + m) * VALD;
#pragma unroll
    for (int kk = 0; kk < 4; ++kk) {
        int k0 = kk * 32 + quad * 8;
        bf16x8 af = *(const bf16x8*)(arow + k0);
        bf16x8 b0 = *(const bf16x8*)(owT + (size_t)(n0 + m) * VALD + k0);
        bf16x8 b1 = *(const bf16x8*)(owT + (size_t)(n0 + 16 + m) * VALD + k0);
        a0 = __builtin_amdgcn_mfma_f32_16x16x32_bf16(af, b0, a0, 0, 0, 0);
        a1 = __builtin_amdgcn_mfma_f32_16x16x32_bf16(af, b1, a1, 0, 0, 0);
    }
#pragma unroll
    for (int r = 0; r < 4; ++r) {
        int row = quad * 4 + r;
        {
            int col = n0 + m;
            float h = a0[r] + ob[col];
            hs[row][col] = h / (1.f + __expf(-h));
        }
        {
            int col = n0 + 16 + m;
            float h = a1[r] + ob[col];
            hs[row][col] = h / (1.f + __expf(-h));
        }
    }
    __syncthreads();
    {
        int row = tid >> 4, seg = tid & 15;
        float s = 0.f, q = 0.f;
#pragma unroll
        for (int j = 0; j < 8; ++j) {
            float v = hs[row][seg * 8 + j];
            s += v; q += v * v;
        }
        ps[row][seg] = s; psq[row][seg] = q;
    }
    __syncthreads();
    if (tid < 16) {
        float s = 0.f, q = 0.f;
#pragma unroll
        for (int j = 0; j < 16; ++j) { s += ps[tid][j]; q += psq[tid][j]; }
        float mu = s * (1.f / 128.f);
        float var = q * (1.f / 128.f) - mu * mu;
        mu_s[tid] = mu;
        rs_s[tid] = rsqrtf(var + 1e-5f);
    }
    __syncthreads();
#pragma unroll
    for (int j = 0; j < 8; ++j) {
        int e = tid + 256 * j;
        int row = e >> 7, col = e & 127;
        out[(size_t)(m0 + row) * VALD + col] =
            (hs[row][col] - mu_s[row]) * rs_s[row] * lng[col] + lnb[col];
    }
}

// ---------------------------------------------------------------------------
extern "C" void kernel_launch(void* const* d_in, const int* in_sizes, int n_in,
                              void* d_out, int out_size, void* d_ws, size_t ws_size,
                              hipStream_t stream) {
    (void)in_sizes; (void)n_in; (void)out_size; (void)ws_size;
    const float* x    = (const float*)d_in[0];
    const float* conn = (const float*)d_in[1];
    const float* kw   = (const float*)d_in[2];
    const float* kb   = (const float*)d_in[3];
    const float* vw   = (const float*)d_in[4];
    const float* vb   = (const float*)d_in[5];
    const float* ow   = (const float*)d_in[6];
    const float* ob   = (const float*)d_in[7];
    const float* lng  = (const float*)d_in[8];
    const float* lnb  = (const float*)d_in[9];
    const int* rows   = (const int*)d_in[10];
    const int* cols   = (const int*)d_in[11];
    float* out        = (float*)d_out;

    char* w = (char*)d_ws;
    auto alloc = [&](size_t bytes) {
        char* p = w;
        w += (bytes + 255) & ~(size_t)255;
        return p;
    };
    uint2* values_pk       = (uint2*)alloc((size_t)NNODE * 512);              // 25.6 MB
    unsigned short* agg_bf = (unsigned short*)alloc((size_t)MTOT * VALD * 2); // 25.6 MB
    float* ksum   = (float*)alloc((size_t)MTOT * 4);
    float* kwsum  = (float*)alloc(256 * 4);
    int*   cursor = (int*)alloc((size_t)NNODE * 4);
    uint2* edge_s = (uint2*)alloc((size_t)NNODE * ECAP * 8);                  // 32 MB
    unsigned short* vwT = (unsigned short*)alloc((size_t)INPD * VALD * 2);
    unsigned short* owT = (unsigned short*)alloc((size_t)VALD * VALD * 2);

    prep_kernel<<<129 + 196, 256, 0, stream>>>(kw, kb, vw, ow, kwsum, vwT, owT, cursor);
    values_build_kernel<<<SBLK + VBLK, 256, 0, stream>>>(
        x, vb, kwsum, vwT, rows, cols, conn, values_pk, ksum, cursor, edge_s);
    aggregate_kernel<<<(NNODE + 7) / 8, 256, 0, stream>>>(
        cursor, edge_s, ksum, values_pk, agg_bf);
    out_kernel<<<MTOT / 16, 256, 0, stream>>>(agg_bf, owT, ob, lng, lnb, out);
}

// Round 12
// 245.131 us; speedup vs baseline: 1.1602x; 1.0779x over previous
//
#include <hip/hip_runtime.h>
#include <hip/hip_bf16.h>

// BatchedSemiAttention: B=2, N=50000, E=800000, INP=128, KEY=64, VAL=128
#define NB    2
#define NNODE 50000
#define NEDGE 800000
#define INPD  128
#define KEYD  64
#define VALD  128
#define MTOT  (NB * NNODE)   // 100000 flattened (b,n) rows
#define VBLK  3125           // NNODE/16 blocks for the values GEMM part
#define EPT   16             // edges per scatter thread (16 independent chains)
#define SBLK  ((NEDGE + 256 * EPT - 1) / (256 * EPT))   // 196 scatter blocks (run FIRST)
#define ECAP  80             // bucket capacity per receiver; E/N=16 Poisson, max~40

typedef __attribute__((ext_vector_type(8))) short bf16x8;
typedef __attribute__((ext_vector_type(4))) float f32x4;

__device__ __forceinline__ unsigned short f2bf(float f) {
    unsigned u = __float_as_uint(f);
    u += 0x7FFFu + ((u >> 16) & 1u);   // RNE
    return (unsigned short)(u >> 16);
}

// ---------------------------------------------------------------------------
// Prep: bf16 transposes of v_w / out_w into [n][k]; kwsum (col-sums of k_w,
// +kb sum at [128]); init the fixed-base edge cursors (cursor[i] = i*ECAP).
// ---------------------------------------------------------------------------
__global__ void prep_kernel(const float* __restrict__ kw, const float* __restrict__ kb,
                            const float* __restrict__ vw, const float* __restrict__ ow,
                            float* __restrict__ kwsum,
                            unsigned short* __restrict__ vwT, unsigned short* __restrict__ owT,
                            int* __restrict__ cursor) {
    int bid = blockIdx.x, tid = threadIdx.x;
    if (bid < 64) {
        int idx = bid * 256 + tid;            // [0,16384)
        int n = idx >> 7, k = idx & 127;
        vwT[idx] = f2bf(vw[k * VALD + n]);
    } else if (bid < 128) {
        int idx = (bid - 64) * 256 + tid;
        int n = idx >> 7, k = idx & 127;
        owT[idx] = f2bf(ow[k * VALD + n]);
    } else if (bid == 128) {
        if (tid < INPD) {
            float s = 0.f;
            for (int j = 0; j < KEYD; ++j) s += kw[tid * KEYD + j];
            kwsum[tid] = s;
        }
        if (tid == 0) {
            float s = 0.f;
            for (int j = 0; j < KEYD; ++j) s += kb[j];
            kwsum[INPD] = s;                  // kbsum
        }
    } else {
        int idx = (bid - 129) * 256 + tid;
        if (idx < NNODE) cursor[idx] = idx * ECAP;
    }
}

// ---------------------------------------------------------------------------
// Values GEMM (both batches, 16 nodes/block, 256 threads) + ksum, with the
// EDGE SCATTER fused as the FIRST SBLK blocks (EPT=16 chains/thread,
// nontemporal 8-B stores). (Round-11 verified kernel, unchanged.)
// ---------------------------------------------------------------------------
__global__ __launch_bounds__(256, 8)
void values_build_kernel(const float* __restrict__ x, const float* __restrict__ vb,
                         const float* __restrict__ kwsum,
                         const unsigned short* __restrict__ vwT,
                         const int* __restrict__ rows_e, const int* __restrict__ cols_e,
                         const float* __restrict__ conn,
                         uint2* __restrict__ values_pk, float* __restrict__ ksum,
                         int* __restrict__ cursor, uint2* __restrict__ edge_s) {
    __shared__ unsigned short xs[32 * 136];   // 8704 B, row stride 272 B
    __shared__ unsigned short pk[16 * 264];   // 8448 B, node stride 528 B
    int tid = threadIdx.x;
    if (blockIdx.x < SBLK) {
        int base = blockIdx.x * 256 + tid;
#pragma unroll
        for (int k = 0; k < EPT; ++k) {
            int e = base + k * (SBLK * 256);
            if (e < NEDGE) {
                int r = rows_e[e];
                int o = atomicAdd(&cursor[r], 1);
                if (o < r * ECAP + ECAP) {    // never false for real data
                    unsigned long long pkd =
                        (unsigned long long)(unsigned)cols_e[e]
                        | ((unsigned long long)__float_as_uint(conn[e]) << 32);
                    __builtin_nontemporal_store(
                        pkd, (unsigned long long*)&edge_s[o]);
                }
            }
        }
        return;
    }
    int node0 = (blockIdx.x - SBLK) * 16;

    // ---- stage: 8 fp32 per batch per thread -> bf16 LDS; fp32 ksum partials
    {
        int row = tid >> 4;            // node_local 0..15
        int cseg = tid & 15;           // 8-float column segment
        const float4* p0 = (const float4*)(x + (size_t)(node0 + row) * INPD) + cseg * 2;
        const float4* p1 = (const float4*)(x + (size_t)(NNODE + node0 + row) * INPD) + cseg * 2;
        float4 u0 = p0[0], u1 = p0[1];
        float4 w0 = p1[0], w1 = p1[1];
        const float4* kwp = (const float4*)kwsum + cseg * 2;
        float4 ka = kwp[0], kc = kwp[1];
        float kp0 = u0.x * ka.x + u0.y * ka.y + u0.z * ka.z + u0.w * ka.w
                  + u1.x * kc.x + u1.y * kc.y + u1.z * kc.z + u1.w * kc.w;
        float kp1 = w0.x * ka.x + w0.y * ka.y + w0.z * ka.z + w0.w * ka.w
                  + w1.x * kc.x + w1.y * kc.y + w1.z * kc.z + w1.w * kc.w;
#pragma unroll
        for (int o = 1; o < 16; o <<= 1) {
            kp0 += __shfl_xor(kp0, o);
            kp1 += __shfl_xor(kp1, o);
        }
        if (cseg == 0) {
            float kb = kwsum[INPD];
            ksum[node0 + row] = kp0 + kb;
            ksum[NNODE + node0 + row] = kp1 + kb;
        }
        union { unsigned short h[8]; uint4 q; } a, b;
        a.h[0] = f2bf(u0.x); a.h[1] = f2bf(u0.y); a.h[2] = f2bf(u0.z); a.h[3] = f2bf(u0.w);
        a.h[4] = f2bf(u1.x); a.h[5] = f2bf(u1.y); a.h[6] = f2bf(u1.z); a.h[7] = f2bf(u1.w);
        b.h[0] = f2bf(w0.x); b.h[1] = f2bf(w0.y); b.h[2] = f2bf(w0.z); b.h[3] = f2bf(w0.w);
        b.h[4] = f2bf(w1.x); b.h[5] = f2bf(w1.y); b.h[6] = f2bf(w1.z); b.h[7] = f2bf(w1.w);
        *(uint4*)(xs + row * 136 + cseg * 8) = a.q;
        *(uint4*)(xs + (16 + row) * 136 + cseg * 8) = b.q;
    }
    __syncthreads();

    int wave = tid >> 6, lane = tid & 63;
    int m = lane & 15, quad = lane >> 4;
    int n0 = wave * 32;                       // this wave's 32-col slice
    f32x4 acc00 = {0.f, 0.f, 0.f, 0.f};      // batch0, cols n0+m
    f32x4 acc01 = {0.f, 0.f, 0.f, 0.f};      // batch0, cols n0+16+m
    f32x4 acc10 = {0.f, 0.f, 0.f, 0.f};      // batch1, cols n0+m
    f32x4 acc11 = {0.f, 0.f, 0.f, 0.f};      // batch1, cols n0+16+m
    const unsigned short* r0 = xs + m * 136;
    const unsigned short* r1 = xs + (16 + m) * 136;
    const unsigned short* bw0 = vwT + (size_t)(n0 + m) * INPD;
    const unsigned short* bw1 = vwT + (size_t)(n0 + 16 + m) * INPD;
#pragma unroll
    for (int kk = 0; kk < 4; ++kk) {
        int k0 = kk * 32 + quad * 8;
        bf16x8 A0 = *(const bf16x8*)(r0 + k0);
        bf16x8 A1 = *(const bf16x8*)(r1 + k0);
        bf16x8 B0 = *(const bf16x8*)(bw0 + k0);
        bf16x8 B1 = *(const bf16x8*)(bw1 + k0);
        acc00 = __builtin_amdgcn_mfma_f32_16x16x32_bf16(A0, B0, acc00, 0, 0, 0);
        acc01 = __builtin_amdgcn_mfma_f32_16x16x32_bf16(A0, B1, acc01, 0, 0, 0);
        acc10 = __builtin_amdgcn_mfma_f32_16x16x32_bf16(A1, B0, acc10, 0, 0, 0);
        acc11 = __builtin_amdgcn_mfma_f32_16x16x32_bf16(A1, B1, acc11, 0, 0, 0);
    }
    int c0 = n0 + m, c1 = n0 + 16 + m;
    float vb0 = vb[c0], vb1 = vb[c1];
    int p0 = (c0 >> 1) * 4 + (c0 & 1);        // ushort index within node's 256
    int p1 = (c1 >> 1) * 4 + (c1 & 1);
#pragma unroll
    for (int r = 0; r < 4; ++r) {
        int nl = quad * 4 + r;                // node_local
        pk[nl * 264 + p0]     = f2bf(acc00[r] + vb0);   // batch 0
        pk[nl * 264 + p0 + 2] = f2bf(acc10[r] + vb0);   // batch 1
        pk[nl * 264 + p1]     = f2bf(acc01[r] + vb1);
        pk[nl * 264 + p1 + 2] = f2bf(acc11[r] + vb1);
    }
    __syncthreads();
    // Coalesced flush skipping the pads: 2 x uint4 per thread = 8 KB.
    {
        int node = tid >> 4, chunk = tid & 15;
        uint4 q0 = *(const uint4*)(pk + node * 264 + chunk * 8);
        uint4 q1 = *(const uint4*)(pk + node * 264 + (chunk + 16) * 8);
        uint4* dst = (uint4*)((char*)values_pk + (size_t)node0 * 512) + node * 32;
        dst[chunk] = q0;
        dst[chunk + 16] = q1;
    }
}

// ---------------------------------------------------------------------------
// FUSED aggregate + out, attempt 2 with the round-6 defects fixed:
//  - 8 nodes/block (grid 6250): gather phase byte-identical in shape to the
//    proven 65-us aggregate (2 rows/wave, x4 unroll) -- r6 halved TLP.
//  - LDS 14.8 KB (r6: 19.4) -> 8 blocks/CU by wave limit.
//  - aggL stride 68 uints (272 B): writes (4row+lane)%32 = 2-way (free);
//    MFMA b128 reads have the same quarter-phase pattern as values_build's
//    proven xs tile (2-way, free) -- r6's conflict source eliminated.
// One barrier set; single out pass (16 rows = 8 nodes x 2 batches).
// Removes out_kernel launch + the 51.2 MB agg_bf HBM round-trip.
// ---------------------------------------------------------------------------
__global__ __launch_bounds__(256)
void aggregate_out_kernel(const int* __restrict__ cursor,
                          const uint2* __restrict__ edge_s,
                          const float* __restrict__ ksum,
                          const uint2* __restrict__ values_pk,
                          const unsigned short* __restrict__ owT,
                          const float* __restrict__ ob,
                          const float* __restrict__ lng, const float* __restrict__ lnb,
                          float* __restrict__ out) {
    __shared__ unsigned aggL[16 * 68];     // 4352 B; row = batch*8 + node_local
    __shared__ float hs[16][VALD + 2];     // 8320 B
    __shared__ float ps[16][16];           // 1024 B
    __shared__ float psq[16][16];          // 1024 B
    __shared__ float mu_s[16], rs_s[16];   // 128 B
    int tid = threadIdx.x;
    int wave = tid >> 6, lane = tid & 63;
    int node_base = blockIdx.x * 8;

    // ---------------- phase 1: aggregation (round-4/8/11 verified body)
    for (int rr = 0; rr < 2; ++rr) {
        int nl = wave * 2 + rr;               // node_local 0..7
        int i = node_base + nl;
        int start = i * ECAP;
        int len = min(cursor[i] - start, ECAP);
        float acc00 = 0.f, acc01 = 0.f, acc10 = 0.f, acc11 = 0.f;
        if (len > 0) {
            if (len <= 64) {
                float ex0 = 0.f, ex1 = 0.f; int colv = 0;
                if (lane < len) {
                    uint2 e = edge_s[start + lane];
                    colv = (int)e.x;
                    float cv = __uint_as_float(e.y);
                    ex0 = __expf(cv * ksum[colv]);
                    ex1 = __expf(cv * ksum[NNODE + colv]);
                }
                float s0 = ex0, s1 = ex1;
#pragma unroll
                for (int o = 1; o < 64; o <<= 1) { s0 += __shfl_xor(s0, o); s1 += __shfl_xor(s1, o); }
                float inv0 = 1.0f / s0, inv1 = 1.0f / s1;
                int p = 0;
                for (; p + 3 < len; p += 4) {
                    int c0 = __shfl(colv, p),     c1 = __shfl(colv, p + 1);
                    int c2 = __shfl(colv, p + 2), c3 = __shfl(colv, p + 3);
                    float wa0 = __shfl(ex0, p) * inv0,     wb0 = __shfl(ex1, p) * inv1;
                    float wa1 = __shfl(ex0, p + 1) * inv0, wb1 = __shfl(ex1, p + 1) * inv1;
                    float wa2 = __shfl(ex0, p + 2) * inv0, wb2 = __shfl(ex1, p + 2) * inv1;
                    float wa3 = __shfl(ex0, p + 3) * inv0, wb3 = __shfl(ex1, p + 3) * inv1;
                    uint2 v0 = values_pk[(size_t)c0 * 64 + lane];
                    uint2 v1 = values_pk[(size_t)c1 * 64 + lane];
                    uint2 v2 = values_pk[(size_t)c2 * 64 + lane];
                    uint2 v3 = values_pk[(size_t)c3 * 64 + lane];
                    acc00 += wa0 * __uint_as_float(v0.x << 16) + wa1 * __uint_as_float(v1.x << 16)
                           + wa2 * __uint_as_float(v2.x << 16) + wa3 * __uint_as_float(v3.x << 16);
                    acc01 += wa0 * __uint_as_float(v0.x & 0xFFFF0000u) + wa1 * __uint_as_float(v1.x & 0xFFFF0000u)
                           + wa2 * __uint_as_float(v2.x & 0xFFFF0000u) + wa3 * __uint_as_float(v3.x & 0xFFFF0000u);
                    acc10 += wb0 * __uint_as_float(v0.y << 16) + wb1 * __uint_as_float(v1.y << 16)
                           + wb2 * __uint_as_float(v2.y << 16) + wb3 * __uint_as_float(v3.y << 16);
                    acc11 += wb0 * __uint_as_float(v0.y & 0xFFFF0000u) + wb1 * __uint_as_float(v1.y & 0xFFFF0000u)
                           + wb2 * __uint_as_float(v2.y & 0xFFFF0000u) + wb3 * __uint_as_float(v3.y & 0xFFFF0000u);
                }
                for (; p < len; ++p) {
                    int c = __shfl(colv, p);
                    float w0 = __shfl(ex0, p) * inv0;
                    float w1 = __shfl(ex1, p) * inv1;
                    uint2 v = values_pk[(size_t)c * 64 + lane];
                    acc00 += w0 * __uint_as_float(v.x << 16);
                    acc01 += w0 * __uint_as_float(v.x & 0xFFFF0000u);
                    acc10 += w1 * __uint_as_float(v.y << 16);
                    acc11 += w1 * __uint_as_float(v.y & 0xFFFF0000u);
                }
            } else {
                float s0 = 0.f, s1 = 0.f;
                for (int basep = 0; basep < len; basep += 64) {
                    int q = basep + lane;
                    if (q < len) {
                        uint2 e = edge_s[start + q];
                        int c = (int)e.x;
                        float cv = __uint_as_float(e.y);
                        s0 += __expf(cv * ksum[c]);
                        s1 += __expf(cv * ksum[NNODE + c]);
                    }
                }
#pragma unroll
                for (int o = 1; o < 64; o <<= 1) { s0 += __shfl_xor(s0, o); s1 += __shfl_xor(s1, o); }
                float inv0 = 1.0f / s0, inv1 = 1.0f / s1;
                for (int p = 0; p < len; ++p) {
                    uint2 e = edge_s[start + p];
                    int c = (int)e.x;
                    float cv = __uint_as_float(e.y);
                    float w0 = __expf(cv * ksum[c]) * inv0;
                    float w1 = __expf(cv * ksum[NNODE + c]) * inv1;
                    uint2 v = values_pk[(size_t)c * 64 + lane];
                    acc00 += w0 * __uint_as_float(v.x << 16);
                    acc01 += w0 * __uint_as_float(v.x & 0xFFFF0000u);
                    acc10 += w1 * __uint_as_float(v.y << 16);
                    acc11 += w1 * __uint_as_float(v.y & 0xFFFF0000u);
                }
            }
        }
        unsigned o0 = ((unsigned)f2bf(acc01) << 16) | (unsigned)f2bf(acc00);
        unsigned o1 = ((unsigned)f2bf(acc11) << 16) | (unsigned)f2bf(acc10);
        aggL[nl * 68 + lane]       = o0;      // batch0 row
        aggL[(8 + nl) * 68 + lane] = o1;      // batch1 row
    }
    __syncthreads();

    // ---------------- phase 2: out = LN(silu(agg @ out_w + ob)) * g + b
    int m = lane & 15, quad = lane >> 4;
    int n0 = wave * 32;
    f32x4 a0 = {0.f, 0.f, 0.f, 0.f}, a1 = {0.f, 0.f, 0.f, 0.f};
    const unsigned short* arow = (const unsigned short*)aggL + m * 136;  // 272 B stride
#pragma unroll
    for (int kk = 0; kk < 4; ++kk) {
        int k0 = kk * 32 + quad * 8;
        bf16x8 af = *(const bf16x8*)(arow + k0);
        bf16x8 b0 = *(const bf16x8*)(owT + (size_t)(n0 + m) * VALD + k0);
        bf16x8 b1 = *(const bf16x8*)(owT + (size_t)(n0 + 16 + m) * VALD + k0);
        a0 = __builtin_amdgcn_mfma_f32_16x16x32_bf16(af, b0, a0, 0, 0, 0);
        a1 = __builtin_amdgcn_mfma_f32_16x16x32_bf16(af, b1, a1, 0, 0, 0);
    }
#pragma unroll
    for (int r = 0; r < 4; ++r) {
        int row = quad * 4 + r;
        {
            int col = n0 + m;
            float h = a0[r] + ob[col];
            hs[row][col] = h / (1.f + __expf(-h));
        }
        {
            int col = n0 + 16 + m;
            float h = a1[r] + ob[col];
            hs[row][col] = h / (1.f + __expf(-h));
        }
    }
    __syncthreads();
    {
        int row = tid >> 4, seg = tid & 15;
        float s = 0.f, q = 0.f;
#pragma unroll
        for (int j = 0; j < 8; ++j) {
            float v = hs[row][seg * 8 + j];
            s += v; q += v * v;
        }
        ps[row][seg] = s; psq[row][seg] = q;
    }
    __syncthreads();
    if (tid < 16) {
        float s = 0.f, q = 0.f;
#pragma unroll
        for (int j = 0; j < 16; ++j) { s += ps[tid][j]; q += psq[tid][j]; }
        float mu = s * (1.f / 128.f);
        float var = q * (1.f / 128.f) - mu * mu;
        mu_s[tid] = mu;
        rs_s[tid] = rsqrtf(var + 1e-5f);
    }
    __syncthreads();
#pragma unroll
    for (int j = 0; j < 8; ++j) {
        int e = tid + 256 * j;
        int row = e >> 7, col = e & 127;             // tile row 0..15
        size_t grow = (row < 8 ? (size_t)(node_base + row)
                               : (size_t)NNODE + node_base + (row - 8));
        out[grow * VALD + col] =
            (hs[row][col] - mu_s[row]) * rs_s[row] * lng[col] + lnb[col];
    }
}

// ---------------------------------------------------------------------------
extern "C" void kernel_launch(void* const* d_in, const int* in_sizes, int n_in,
                              void* d_out, int out_size, void* d_ws, size_t ws_size,
                              hipStream_t stream) {
    (void)in_sizes; (void)n_in; (void)out_size; (void)ws_size;
    const float* x    = (const float*)d_in[0];
    const float* conn = (const float*)d_in[1];
    const float* kw   = (const float*)d_in[2];
    const float* kb   = (const float*)d_in[3];
    const float* vw   = (const float*)d_in[4];
    const float* vb   = (const float*)d_in[5];
    const float* ow   = (const float*)d_in[6];
    const float* ob   = (const float*)d_in[7];
    const float* lng  = (const float*)d_in[8];
    const float* lnb  = (const float*)d_in[9];
    const int* rows   = (const int*)d_in[10];
    const int* cols   = (const int*)d_in[11];
    float* out        = (float*)d_out;

    char* w = (char*)d_ws;
    auto alloc = [&](size_t bytes) {
        char* p = w;
        w += (bytes + 255) & ~(size_t)255;
        return p;
    };
    uint2* values_pk = (uint2*)alloc((size_t)NNODE * 512);          // 25.6 MB
    float* ksum   = (float*)alloc((size_t)MTOT * 4);
    float* kwsum  = (float*)alloc(256 * 4);
    int*   cursor = (int*)alloc((size_t)NNODE * 4);
    uint2* edge_s = (uint2*)alloc((size_t)NNODE * ECAP * 8);        // 32 MB
    unsigned short* vwT = (unsigned short*)alloc((size_t)INPD * VALD * 2);
    unsigned short* owT = (unsigned short*)alloc((size_t)VALD * VALD * 2);

    prep_kernel<<<129 + 196, 256, 0, stream>>>(kw, kb, vw, ow, kwsum, vwT, owT, cursor);
    values_build_kernel<<<SBLK + VBLK, 256, 0, stream>>>(
        x, vb, kwsum, vwT, rows, cols, conn, values_pk, ksum, cursor, edge_s);
    aggregate_out_kernel<<<NNODE / 8, 256, 0, stream>>>(
        cursor, edge_s, ksum, values_pk, owT, ob, lng, lnb, out);
}